// Round 3
// baseline (448.201 us; speedup 1.0000x reference)
//
#include <hip/hip_runtime.h>

// VQ-VAE codebook quantization, MI355X (gfx950)
// z: [32, 256, 32, 32] fp32 ; codebook: [1024, 256] fp32
// outputs (concat fp32): z_q [32,256,32,32] (8388608) | idx [32768] | loss [1]
//
// idx contract: match numpy fp32 argmin of dist = fl( fl(znorm+enorm) - 2*dot ),
// ties -> lowest index. The +znorm(~256) quantizes dist to ulp ~1.5e-5;
// replicating that double-rounding is what makes ties match (verified R2).

#define D_DIM   256
#define K_CODES 1024
#define HW      1024
#define MT      128     // positions per block
#define NT      256     // codes per N-chunk
#define NTP     260     // padded Es row stride (260%32=4 -> store conflicts 2-way=free)
#define BK      16      // d-chunk per barrier
#define THREADS 1024    // 16 waves -> 4/SIMD (needs VGPR<=128; tile sized for ~90)

#define IDX_OFF  8388608
#define LOSS_OFF 8421376

// LDS (floats): As[256*128] | enorm_lds[1024] | Es[16*260] | bestm[128] | znorm_s[128]
#define AS_F   (D_DIM*MT)                              // 32768
#define EN_F   (K_CODES)                               // 1024
#define ES_F   (BK*NTP)                                // 4160 (also holds 1024 fp64 znorm partials = 2048 slots)
#define SMEM_FLOATS (AS_F + EN_F + ES_F + MT + MT)     // 38208
#define SMEM_BYTES  (SMEM_FLOATS * 4)                  // 152832 B < 160 KiB

extern __shared__ float smem[];

__global__ __launch_bounds__(THREADS, 4) void vq_kernel(
        const float* __restrict__ z, const float* __restrict__ cb,
        float* __restrict__ out)
{
    float* As        = smem;                     // [256][128]
    float* enorm_lds = smem + AS_F;              // [1024]
    float* Es        = smem + AS_F + EN_F;       // [16][260]
    int*   bestm     = (int*)(smem + AS_F + EN_F + ES_F);        // [128]
    float* znorm_s   = smem + AS_F + EN_F + ES_F + MT;           // [128]

    const int t   = threadIdx.x;
    const int blk = blockIdx.x;          // 256 blocks = 1/CU
    const int b   = blk >> 3;
    const int p0  = (blk & 7) * MT;
    const float* zb = z + (size_t)b * D_DIM * HW;

    // prefetch E tile 0 into registers (hides L2 latency under A-staging/znorm)
    const int ek  = t >> 2;              // code row 0..255 (4 lanes/row -> 64B coalesced)
    const int ed4 = t & 3;               // which float4 of the 16-d chunk
    float4 vnext = *(const float4*)(cb + (size_t)ek * D_DIM + ed4 * 4);

    // ---- stage A^T [256][128], z read from HBM once, coalesced float4 ----
    for (int i = t; i < D_DIM * MT / 4; i += THREADS) {
        int d = i >> 5, m4 = i & 31;
        *(float4*)(As + d * MT + m4 * 4) = *(const float4*)(zb + d * HW + p0 + m4 * 4);
    }
    __syncthreads();

    // ---- znorm[m]: fp64 column sum (<=1-2 ulp vs np pairwise -> uniform per-row
    //      exact-ulp shift -> argmin invariant) ----
    {
        int m = t & (MT - 1), q = t >> 7;            // 8 segments x 32 d
        const float* col = As + m;
        double zp = 0.0;
        #pragma unroll 8
        for (int d = q * 32; d < q * 32 + 32; ++d) {
            double v = (double)col[d * MT];          // 2 lanes/bank = free
            zp = fma(v, v, zp);
        }
        double* zscr = (double*)Es;                  // 1024 doubles = 8 KB, fits Es
        zscr[q * MT + m] = zp;
    }
    __syncthreads();
    if (t < MT) {
        double* zscr = (double*)Es;
        double s = ((zscr[t] + zscr[MT + t]) + (zscr[2*MT + t] + zscr[3*MT + t]))
                 + ((zscr[4*MT + t] + zscr[5*MT + t]) + (zscr[6*MT + t] + zscr[7*MT + t]));
        znorm_s[t] = (float)s;
    }

    // ---- enorm in-kernel, bit-identical to R2's enorm_kernel per-row sequence
    //      (float4 fmaf chain + 6-step xor tree) ----
    {
        int w = t >> 6, lane = t & 63;
        #pragma unroll 4
        for (int r = 0; r < 64; ++r) {
            int k = w * 64 + r;
            float4 v = *(const float4*)(cb + (size_t)k * D_DIM + lane * 4);
            float s = fmaf(v.x, v.x, fmaf(v.y, v.y, fmaf(v.z, v.z, v.w * v.w)));
            #pragma unroll
            for (int off = 32; off; off >>= 1) s += __shfl_xor(s, off);
            if (lane == 0) enorm_lds[k] = s;
        }
    }
    __syncthreads();   // znorm_s + enorm_lds ready; zscr region reusable as Es

    const int tx = t & 63, ty = t >> 6;  // wave = one ty group -> A reads broadcast
    const int m_base = ty * 8;           // 16 ty x 8 = 128 positions
    const int kx = tx * 4;               // 64 tx x 4 = 256 codes (16B lane stride: conflict-free)

    float znf[8];
    #pragma unroll
    for (int i = 0; i < 8; ++i) znf[i] = znorm_s[m_base + i];

    float bestv[8]; int besti[8];
    #pragma unroll
    for (int i = 0; i < 8; ++i) { bestv[i] = 3.4e38f; besti[i] = 0; }

    float acc[8][4];

    // ---- GEMM: 64 tiles = 4 k-chunks x 16 d-chunks, reg-prefetched E staging ----
    for (int s = 0; s < 64; ++s) {
        __syncthreads();                 // all waves done reading previous Es tile
        {
            int r0 = ed4 * 4;            // stores: (16*ed4 + 4r + kk)%32 -> 2-way = free
            Es[(r0 + 0) * NTP + ek] = vnext.x;
            Es[(r0 + 1) * NTP + ek] = vnext.y;
            Es[(r0 + 2) * NTP + ek] = vnext.z;
            Es[(r0 + 3) * NTP + ek] = vnext.w;
        }
        __syncthreads();
        if (s < 63) {                    // prefetch next tile (L2-resident codebook)
            int s1 = s + 1, c1 = s1 >> 4, dk1 = (s1 & 15) * BK;
            vnext = *(const float4*)(cb + (size_t)(c1 * NT + ek) * D_DIM + dk1 + ed4 * 4);
        }
        if ((s & 15) == 0) {
            #pragma unroll
            for (int i = 0; i < 8; ++i)
                #pragma unroll
                for (int j = 0; j < 4; ++j) acc[i][j] = 0.f;
        }
        const int dka = (s & 15) * BK;
        #pragma unroll
        for (int dd = 0; dd < BK; ++dd) {
            float a[8], e[4];
            *(float4*)(a)     = *(const float4*)(As + (dka + dd) * MT + m_base);     // broadcast
            *(float4*)(a + 4) = *(const float4*)(As + (dka + dd) * MT + m_base + 4); // broadcast
            *(float4*)(e)     = *(const float4*)(Es + dd * NTP + kx);                // min-phase
            #pragma unroll
            for (int i = 0; i < 8; ++i)
                #pragma unroll
                for (int j = 0; j < 4; ++j)
                    acc[i][j] = fmaf(a[i], e[j], acc[i][j]);
        }
        if ((s & 15) == 15) {            // chunk epilogue: np-style double rounding
            int k0 = (s >> 4) * NT;
            #pragma unroll
            for (int j = 0; j < 4; ++j) {
                float bn = enorm_lds[k0 + kx + j];
                int kidx = k0 + kx + j;
                #pragma unroll
                for (int i = 0; i < 8; ++i) {
                    float A   = znf[i] + bn;           // rounds at ~256 scale
                    float val = A - 2.0f * acc[i][j];  // 2*acc exact; single rounding
                    if (val < bestv[i] || (val == bestv[i] && kidx < besti[i])) {
                        bestv[i] = val; besti[i] = kidx;
                    }
                }
            }
        }
    }

    // ---- argmin across the 64-lane k dimension, lowest index on ties ----
    #pragma unroll
    for (int i = 0; i < 8; ++i) {
        float v = bestv[i]; int ix = besti[i];
        #pragma unroll
        for (int off = 32; off; off >>= 1) {
            float ov = __shfl_xor(v, off);
            int   oi = __shfl_xor(ix, off);
            if (ov < v || (ov == v && oi < ix)) { v = ov; ix = oi; }
        }
        if (tx == 0) {
            bestm[m_base + i] = ix;
            out[IDX_OFF + (size_t)blk * MT + m_base + i] = (float)ix;
        }
    }
    __syncthreads();

    // ---- epilogue: gather codebook rows (L2), write z_q coalesced, loss ----
    float lsum = 0.f;
    const size_t zq_base = (size_t)b * D_DIM * HW + p0;
    for (int i2 = t; i2 < D_DIM * MT / 4; i2 += THREADS) {
        int p = i2 & (MT - 1), d4 = i2 >> 7;
        int idx = bestm[p];
        float4 cv = *(const float4*)(cb + (size_t)idx * D_DIM + d4 * 4);
        float z0 = As[(d4 * 4 + 0) * MT + p];
        float z1 = As[(d4 * 4 + 1) * MT + p];
        float z2 = As[(d4 * 4 + 2) * MT + p];
        float z3 = As[(d4 * 4 + 3) * MT + p];
        float e0 = cv.x - z0, e1 = cv.y - z1, e2 = cv.z - z2, e3 = cv.w - z3;
        lsum = fmaf(e0, e0, lsum); lsum = fmaf(e1, e1, lsum);
        lsum = fmaf(e2, e2, lsum); lsum = fmaf(e3, e3, lsum);
        out[zq_base + (size_t)(d4 * 4 + 0) * HW + p] = cv.x;
        out[zq_base + (size_t)(d4 * 4 + 1) * HW + p] = cv.y;
        out[zq_base + (size_t)(d4 * 4 + 2) * HW + p] = cv.z;
        out[zq_base + (size_t)(d4 * 4 + 3) * HW + p] = cv.w;
    }
    #pragma unroll
    for (int off = 32; off; off >>= 1) lsum += __shfl_xor(lsum, off);
    __syncthreads();
    if ((t & 63) == 0) Es[t >> 6] = lsum;   // 16 wave partials
    __syncthreads();
    if (t == 0) {
        float ssum = 0.f;
        #pragma unroll
        for (int w = 0; w < 16; ++w) ssum += Es[w];
        atomicAdd(out + LOSS_OFF, ssum * (1.25f / 8388608.f));
    }
}

extern "C" void kernel_launch(void* const* d_in, const int* in_sizes, int n_in,
                              void* d_out, int out_size, void* d_ws, size_t ws_size,
                              hipStream_t stream) {
    const float* z  = (const float*)d_in[0];
    const float* cb = (const float*)d_in[1];
    float* out = (float*)d_out;

    // loss slot accumulated via atomics -> zero it (d_out poisoned 0xAA each launch)
    hipMemsetAsync(out + LOSS_OFF, 0, sizeof(float), stream);

    hipFuncSetAttribute((const void*)vq_kernel,
                        hipFuncAttributeMaxDynamicSharedMemorySize, SMEM_BYTES);
    vq_kernel<<<256, THREADS, SMEM_BYTES, stream>>>(z, cb, out);
}

// Round 4
// 341.177 us; speedup vs baseline: 1.3137x; 1.3137x over previous
//
#include <hip/hip_runtime.h>

// VQ-VAE codebook quantization, MI355X (gfx950)
// z: [32, 256, 32, 32] fp32 ; codebook: [1024, 256] fp32
// outputs (concat fp32): z_q [32,256,32,32] (8388608) | idx [32768] | loss [1]
//
// idx contract: match numpy fp32 argmin of dist = fl( fl(znorm+enorm) - 2*dot ),
// ties -> lowest index (verified R2/R3). enorm bit pattern must match R2's
// enorm_kernel; znorm in fp64 (uniform exact-ulp row shift -> argmin invariant).
//
// NOTE __launch_bounds__ 2nd arg is CUDA-semantics min BLOCKS/CU (R3 post-mortem:
// (1024,4) -> 64-VGPR cap -> spills -> 192/364 MB scratch traffic). (1024,1)
// gives the 128-VGPR cap that a 1024-thread block requires; LDS (148.7 KB)
// already limits to 1 block/CU, so VGPR is occupancy-free up to 128.

#define D_DIM   256
#define K_CODES 1024
#define HW      1024
#define MT      128     // positions per block
#define NT      256     // codes per N-chunk
#define NTP     260     // padded Es row stride (stores 2-way = free; rows stay 16B-aligned)
#define BK      16      // d-chunk per barrier
#define THREADS 1024    // 16 waves = 4/SIMD (1 block/CU via LDS)

#define IDX_OFF  8388608
#define LOSS_OFF 8421376

// LDS (floats): As[256*128] | Es[16*260] | bestm[128] | znorm_s[128]
#define AS_F   (D_DIM*MT)                          // 32768
#define ES_F   (BK*NTP)                            // 4160 (>= 1024 fp64 znorm partials = 2048 floats)
#define SMEM_FLOATS (AS_F + ES_F + MT + MT)        // 37184
#define SMEM_BYTES  (SMEM_FLOATS * 4)              // 148736 B < 160 KiB

extern __shared__ float smem[];

// enorm[k] = fp32 sum of cb[k][d]^2 — KEEP BIT-IDENTICAL to R2 (passed):
// per-lane float4 fmaf chain + 6-step xor tree.
__global__ void enorm_kernel(const float* __restrict__ cb, float* __restrict__ enorm) {
    int gt = blockIdx.x * blockDim.x + threadIdx.x;
    int k = gt >> 6;
    int lane = gt & 63;
    const float4* row = (const float4*)(cb + (size_t)k * D_DIM);
    float4 v = row[lane];
    float s = fmaf(v.x, v.x, fmaf(v.y, v.y, fmaf(v.z, v.z, v.w * v.w)));
    #pragma unroll
    for (int off = 32; off; off >>= 1) s += __shfl_xor(s, off);
    if (lane == 0) enorm[k] = s;
}

__global__ __launch_bounds__(THREADS, 1) void vq_kernel(
        const float* __restrict__ z, const float* __restrict__ cb,
        const float* __restrict__ enorm, float* __restrict__ out)
{
    float* As      = smem;                           // [256][128]
    float* Es      = smem + AS_F;                    // [16][260]
    int*   bestm   = (int*)(smem + AS_F + ES_F);     // [128]
    float* znorm_s = smem + AS_F + ES_F + MT;        // [128]

    const int t   = threadIdx.x;
    const int blk = blockIdx.x;          // 256 blocks = 1/CU
    const int b   = blk >> 3;
    const int p0  = (blk & 7) * MT;
    const float* zb = z + (size_t)b * D_DIM * HW;

    // prefetch E tile 0 into registers (hides L2 latency under A-staging/znorm)
    const int ek  = t >> 2;              // code row 0..255 (4 lanes/row -> 64B coalesced)
    const int ed4 = t & 3;               // which float4 of the 16-d chunk
    float4 vnext = *(const float4*)(cb + (size_t)ek * D_DIM + ed4 * 4);

    // ---- stage A^T [256][128], z read from HBM once, coalesced float4 ----
    for (int i = t; i < D_DIM * MT / 4; i += THREADS) {
        int d = i >> 5, m4 = i & 31;
        *(float4*)(As + d * MT + m4 * 4) = *(const float4*)(zb + d * HW + p0 + m4 * 4);
    }
    __syncthreads();

    // ---- znorm[m]: fp64 column sum -> fp32 ----
    {
        int m = t & (MT - 1), q = t >> 7;            // 8 segments x 32 d
        const float* col = As + m;
        double zp = 0.0;
        #pragma unroll 8
        for (int d = q * 32; d < q * 32 + 32; ++d) {
            double v = (double)col[d * MT];          // 2 lanes/bank = free
            zp = fma(v, v, zp);
        }
        double* zscr = (double*)Es;                  // 1024 doubles = 8 KB, fits Es
        zscr[q * MT + m] = zp;
    }
    __syncthreads();
    if (t < MT) {
        double* zscr = (double*)Es;
        double s = ((zscr[t] + zscr[MT + t]) + (zscr[2*MT + t] + zscr[3*MT + t]))
                 + ((zscr[4*MT + t] + zscr[5*MT + t]) + (zscr[6*MT + t] + zscr[7*MT + t]));
        znorm_s[t] = (float)s;
    }
    __syncthreads();

    const int tx = t & 63, ty = t >> 6;  // ty == wave id -> A reads are wave broadcasts
    const int m_base = ty * 8;           // 16 ty x 8 = 128 positions
    const int kx = tx * 4;               // 64 tx x 4 = 256 codes; 16B lane stride = conflict-free

    float znf[8];
    #pragma unroll
    for (int i = 0; i < 8; ++i) znf[i] = znorm_s[m_base + i];

    // prefetch this thread's 16 enorm values (avoids mid-GEMM global stalls)
    float4 bn4[4];
    #pragma unroll
    for (int c = 0; c < 4; ++c) bn4[c] = *(const float4*)(enorm + c * NT + kx);

    float bestv[8]; int besti[8];
    #pragma unroll
    for (int i = 0; i < 8; ++i) { bestv[i] = 3.4e38f; besti[i] = 0; }

    float acc[8][4];

    // ---- GEMM: 64 tiles = 4 k-chunks x 16 d-chunks, reg-prefetched E staging ----
    for (int s = 0; s < 64; ++s) {
        __syncthreads();                 // all waves done reading previous Es tile
        {
            int r0 = ed4 * 4;            // stores 2-way aliased = free (NTP=260)
            Es[(r0 + 0) * NTP + ek] = vnext.x;
            Es[(r0 + 1) * NTP + ek] = vnext.y;
            Es[(r0 + 2) * NTP + ek] = vnext.z;
            Es[(r0 + 3) * NTP + ek] = vnext.w;
        }
        __syncthreads();
        if (s < 63) {                    // prefetch next tile (L2-resident codebook)
            int s1 = s + 1, c1 = s1 >> 4, dk1 = (s1 & 15) * BK;
            vnext = *(const float4*)(cb + (size_t)(c1 * NT + ek) * D_DIM + dk1 + ed4 * 4);
        }
        if ((s & 15) == 0) {
            #pragma unroll
            for (int i = 0; i < 8; ++i)
                #pragma unroll
                for (int j = 0; j < 4; ++j) acc[i][j] = 0.f;
        }
        const int dka = (s & 15) * BK;
        #pragma unroll
        for (int dd = 0; dd < BK; ++dd) {
            float a[8], e[4];
            *(float4*)(a)     = *(const float4*)(As + (dka + dd) * MT + m_base);     // broadcast
            *(float4*)(a + 4) = *(const float4*)(As + (dka + dd) * MT + m_base + 4); // broadcast
            *(float4*)(e)     = *(const float4*)(Es + dd * NTP + kx);                // min-phase
            #pragma unroll
            for (int i = 0; i < 8; ++i)
                #pragma unroll
                for (int j = 0; j < 4; ++j)
                    acc[i][j] = fmaf(a[i], e[j], acc[i][j]);
        }
        if ((s & 15) == 15) {            // chunk epilogue: np-style double rounding
            int c = s >> 4;
            int k0 = c * NT;
            const float* bnp = (const float*)&bn4[c];
            #pragma unroll
            for (int j = 0; j < 4; ++j) {
                float bn = bnp[j];
                int kidx = k0 + kx + j;
                #pragma unroll
                for (int i = 0; i < 8; ++i) {
                    float A   = znf[i] + bn;           // rounds at ~256 scale
                    float val = A - 2.0f * acc[i][j];  // 2*acc exact; single rounding
                    if (val < bestv[i] || (val == bestv[i] && kidx < besti[i])) {
                        bestv[i] = val; besti[i] = kidx;
                    }
                }
            }
        }
    }

    // ---- argmin across the 64-lane k dimension, lowest index on ties ----
    #pragma unroll
    for (int i = 0; i < 8; ++i) {
        float v = bestv[i]; int ix = besti[i];
        #pragma unroll
        for (int off = 32; off; off >>= 1) {
            float ov = __shfl_xor(v, off);
            int   oi = __shfl_xor(ix, off);
            if (ov < v || (ov == v && oi < ix)) { v = ov; ix = oi; }
        }
        if (tx == 0) {
            bestm[m_base + i] = ix;
            out[IDX_OFF + (size_t)blk * MT + m_base + i] = (float)ix;
        }
    }
    __syncthreads();

    // ---- epilogue: gather codebook rows (L2), write z_q coalesced, loss ----
    float lsum = 0.f;
    const size_t zq_base = (size_t)b * D_DIM * HW + p0;
    for (int i2 = t; i2 < D_DIM * MT / 4; i2 += THREADS) {
        int p = i2 & (MT - 1), d4 = i2 >> 7;
        int idx = bestm[p];
        float4 cv = *(const float4*)(cb + (size_t)idx * D_DIM + d4 * 4);
        float z0 = As[(d4 * 4 + 0) * MT + p];
        float z1 = As[(d4 * 4 + 1) * MT + p];
        float z2 = As[(d4 * 4 + 2) * MT + p];
        float z3 = As[(d4 * 4 + 3) * MT + p];
        float e0 = cv.x - z0, e1 = cv.y - z1, e2 = cv.z - z2, e3 = cv.w - z3;
        lsum = fmaf(e0, e0, lsum); lsum = fmaf(e1, e1, lsum);
        lsum = fmaf(e2, e2, lsum); lsum = fmaf(e3, e3, lsum);
        out[zq_base + (size_t)(d4 * 4 + 0) * HW + p] = cv.x;
        out[zq_base + (size_t)(d4 * 4 + 1) * HW + p] = cv.y;
        out[zq_base + (size_t)(d4 * 4 + 2) * HW + p] = cv.z;
        out[zq_base + (size_t)(d4 * 4 + 3) * HW + p] = cv.w;
    }
    #pragma unroll
    for (int off = 32; off; off >>= 1) lsum += __shfl_xor(lsum, off);
    __syncthreads();
    if ((t & 63) == 0) Es[t >> 6] = lsum;   // 16 wave partials
    __syncthreads();
    if (t == 0) {
        float ssum = 0.f;
        #pragma unroll
        for (int w = 0; w < 16; ++w) ssum += Es[w];
        atomicAdd(out + LOSS_OFF, ssum * (1.25f / 8388608.f));
    }
}

extern "C" void kernel_launch(void* const* d_in, const int* in_sizes, int n_in,
                              void* d_out, int out_size, void* d_ws, size_t ws_size,
                              hipStream_t stream) {
    const float* z  = (const float*)d_in[0];
    const float* cb = (const float*)d_in[1];
    float* out = (float*)d_out;
    float* enorm = (float*)d_ws;

    // loss slot accumulated via atomics -> zero it (d_out poisoned 0xAA each launch)
    hipMemsetAsync(out + LOSS_OFF, 0, sizeof(float), stream);

    enorm_kernel<<<256, 256, 0, stream>>>(cb, enorm);

    hipFuncSetAttribute((const void*)vq_kernel,
                        hipFuncAttributeMaxDynamicSharedMemorySize, SMEM_BYTES);
    vq_kernel<<<256, THREADS, SMEM_BYTES, stream>>>(z, cb, enorm, out);
}